// Round 8
// baseline (123.541 us; speedup 1.0000x reference)
//
#include <hip/hip_runtime.h>
#include <math.h>

// ---------------------------------------------------------------------------
// RootCauseAttention: per-node scores -> edge segment-sum -> global softmax
//
// Structure (round 8 == round 7 + compile fix):
//  K1 node_scores: s_src, t_dst(=s_dst+b_edge), self(=s_node+b_node); 16
//     lanes/node, float4 loads.
//  K2 edge_bin: LDS histograms, NO global atomics (rounds 1-2: global fp32
//     atomics run ~18 G/s memory-side RMW regardless of scope). Grid
//     (B=128 chunks) x (R=4 ranges of 16384), 1024 thr/block, 64 KB LDS ->
//     2 blocks/CU = 32 waves/CU (round 6 ran 256 blocks = 1 block/CU; the
//     loop is latency-bound on random L2 gathers, so max occupancy matters).
//     src+dst rows loaded int4 unconditionally; gather+LDS-atomic
//     predicated. Non-temporal writeout of partials via native clang vector
//     type (HIP float4 is a class -> rejected by the builtin).
//  K3 combine_stats: acc = self + sum_b partials; ONLINE softmax stats
//     (m,l) per block -> red[256|256]. No atomics, no grid.sync (round 4:
//     grid.sync spins ~59 us on this 8-XCD chip).
//  K4 finalize: every block redundantly reduces the 256 (m,l) pairs (2 KB,
//     L2-hot) -> (M,L), writes out = exp(acc-M)/L.
//
// Workspace (floats): s_src[N] | t_dst[N] | self[N] | acc[N] | red[512] |
//                     partials[B*N]
// ---------------------------------------------------------------------------

#define RANGE_BITS 14
#define RANGE_SIZE (1 << RANGE_BITS)   // 16384 nodes/range, 64 KB LDS
#define NCHUNKS 128
#define STAT_BLOCKS 256                // K3 grid size (fixed; red[] sizing)

typedef float vfloat4 __attribute__((ext_vector_type(4)));

// ---------------- K1: node scores (16 lanes/node, float4) ------------------
__global__ __launch_bounds__(256) void node_scores_kernel(
    const float* __restrict__ h,
    const float* __restrict__ W_edge,   // [2H]
    const float* __restrict__ b_edge,   // [1]
    const float* __restrict__ W_node,   // [H]
    const float* __restrict__ b_node,   // [1]
    float* __restrict__ s_src,
    float* __restrict__ t_dst,
    float* __restrict__ self_sc,
    float* __restrict__ acc,            // pre-init to self (fallback path)
    int N, int H)
{
    const int lane16 = threadIdx.x & 15;
    const int n = (blockIdx.x * blockDim.x + threadIdx.x) >> 4;
    if (n >= N) return;

    const float4* __restrict__ h4  = (const float4*)(h + (size_t)n * H);
    const float4* __restrict__ ws4 = (const float4*)(W_edge);
    const float4* __restrict__ wd4 = (const float4*)(W_edge + H);
    const float4* __restrict__ wn4 = (const float4*)(W_node);
    const int H4 = H >> 2;

    float ps = 0.0f, pd = 0.0f, pn = 0.0f;
    for (int i = lane16; i < H4; i += 16) {
        float4 hv = h4[i];
        float4 a = ws4[i], b = wd4[i], c = wn4[i];
        ps = fmaf(hv.x, a.x, fmaf(hv.y, a.y, fmaf(hv.z, a.z, fmaf(hv.w, a.w, ps))));
        pd = fmaf(hv.x, b.x, fmaf(hv.y, b.y, fmaf(hv.z, b.z, fmaf(hv.w, b.w, pd))));
        pn = fmaf(hv.x, c.x, fmaf(hv.y, c.y, fmaf(hv.z, c.z, fmaf(hv.w, c.w, pn))));
    }
    #pragma unroll
    for (int off = 8; off > 0; off >>= 1) {
        ps += __shfl_xor(ps, off, 64);
        pd += __shfl_xor(pd, off, 64);
        pn += __shfl_xor(pn, off, 64);
    }
    if (lane16 == 0) {
        float self = pn + b_node[0];
        s_src[n]   = ps;
        t_dst[n]   = pd + b_edge[0];
        self_sc[n] = self;
        acc[n]     = self;
    }
}

// ---------------- K2: LDS-histogram edge binning ---------------------------
__global__ __launch_bounds__(1024) void edge_bin_kernel(
    const int* __restrict__ ei,          // [2*E]: src row then dst row
    const float* __restrict__ s_src,
    const float* __restrict__ t_dst,
    float* __restrict__ partials,        // [B*N]
    int N, int E, int chunk, int vec_ok)
{
    __shared__ float hist[RANGE_SIZE];
    const int b  = blockIdx.x;
    const int r  = blockIdx.y;
    const int lo = r << RANGE_BITS;
    const int hi = min(lo + RANGE_SIZE, N);
    const unsigned span = (unsigned)(hi - lo);

    {   // vector zeroing
        vfloat4* __restrict__ hz = (vfloat4*)hist;
        const vfloat4 z = {0.0f, 0.0f, 0.0f, 0.0f};
        for (int i = threadIdx.x; i < (RANGE_SIZE >> 2); i += blockDim.x)
            hz[i] = z;
    }
    __syncthreads();

    const int e0 = b * chunk;
    const int e1 = min(e0 + chunk, E);
    if (e0 < e1) {
        if (vec_ok) {
            const int nvec = (e1 - e0) >> 2;
            const int4* __restrict__ dst4 = (const int4*)(ei + E + e0);
            const int4* __restrict__ src4 = (const int4*)(ei + e0);
            for (int i = threadIdx.x; i < nvec; i += blockDim.x) {
                int4 d = dst4[i];
                int4 s = src4[i];
                unsigned ux = (unsigned)(d.x - lo), uy = (unsigned)(d.y - lo);
                unsigned uz = (unsigned)(d.z - lo), uw = (unsigned)(d.w - lo);
                if (ux < span) atomicAdd(&hist[ux], s_src[s.x] + t_dst[d.x]);
                if (uy < span) atomicAdd(&hist[uy], s_src[s.y] + t_dst[d.y]);
                if (uz < span) atomicAdd(&hist[uz], s_src[s.z] + t_dst[d.z]);
                if (uw < span) atomicAdd(&hist[uw], s_src[s.w] + t_dst[d.w]);
            }
            for (int e = e0 + 4 * nvec + threadIdx.x; e < e1; e += blockDim.x) {
                int d = ei[E + e];
                unsigned u = (unsigned)(d - lo);
                if (u < span) atomicAdd(&hist[u], s_src[ei[e]] + t_dst[d]);
            }
        } else {
            for (int e = e0 + threadIdx.x; e < e1; e += blockDim.x) {
                int d = ei[E + e];
                unsigned u = (unsigned)(d - lo);
                if (u < span) atomicAdd(&hist[u], s_src[ei[e]] + t_dst[d]);
            }
        }
    }
    __syncthreads();

    float* __restrict__ outp = partials + (size_t)b * N + lo;
    const int len = hi - lo;
    if ((len & 3) == 0) {
        const int len4 = len >> 2;
        const vfloat4* __restrict__ h4 = (const vfloat4*)hist;
        vfloat4* __restrict__ o4 = (vfloat4*)outp;
        for (int i = threadIdx.x; i < len4; i += blockDim.x)
            __builtin_nontemporal_store(h4[i], &o4[i]);
    } else {
        for (int i = threadIdx.x; i < len; i += blockDim.x)
            __builtin_nontemporal_store(hist[i], &outp[i]);
    }
}

// Fallback edge path (tiny workspace): agent-scope atomics into acc.
__global__ __launch_bounds__(256) void edge_accum_fallback_kernel(
    const int* __restrict__ ei,
    const float* __restrict__ s_src,
    const float* __restrict__ t_dst,
    float* __restrict__ acc,
    int E)
{
    int e = blockIdx.x * blockDim.x + threadIdx.x;
    if (e >= E) return;
    int s = ei[e];
    int d = ei[E + e];
    atomicAdd(&acc[d], s_src[s] + t_dst[d]);
}

// ---------------- block reduction helpers ----------------------------------
__device__ __forceinline__ float blockReduceMaxB(float v) {
    __shared__ float sm[16];
    #pragma unroll
    for (int off = 32; off > 0; off >>= 1) v = fmaxf(v, __shfl_xor(v, off, 64));
    const int w = threadIdx.x >> 6, l = threadIdx.x & 63;
    const int nw = blockDim.x >> 6;
    if (l == 0) sm[w] = v;
    __syncthreads();
    float r = sm[0];
    for (int i = 1; i < nw; ++i) r = fmaxf(r, sm[i]);
    __syncthreads();
    return r;
}

__device__ __forceinline__ float blockReduceSumB(float v) {
    __shared__ float sm[16];
    #pragma unroll
    for (int off = 32; off > 0; off >>= 1) v += __shfl_xor(v, off, 64);
    const int w = threadIdx.x >> 6, l = threadIdx.x & 63;
    const int nw = blockDim.x >> 6;
    if (l == 0) sm[w] = v;
    __syncthreads();
    float r = 0.0f;
    for (int i = 0; i < nw; ++i) r += sm[i];
    __syncthreads();
    return r;
}

// ---------------- K3: combine + online softmax stats -----------------------
// Grid MUST be STAT_BLOCKS blocks. red[b] = m_b, red[STAT_BLOCKS+b] = l_b.
__global__ __launch_bounds__(256) void combine_stats_kernel(
    const float* __restrict__ self_sc,
    const float* __restrict__ partials,
    float* __restrict__ acc,
    float* __restrict__ red,
    int N, int B, int use_partials)
{
    float m = -INFINITY, l = 0.0f;
    for (int i = blockIdx.x * blockDim.x + threadIdx.x; i < N;
         i += gridDim.x * blockDim.x) {
        float v;
        if (use_partials) {
            float v0 = self_sc[i], v1 = 0.0f, v2 = 0.0f, v3 = 0.0f;
            int b = 0;
            for (; b + 4 <= B; b += 4) {
                v0 += __builtin_nontemporal_load(&partials[(size_t)(b + 0) * N + i]);
                v1 += __builtin_nontemporal_load(&partials[(size_t)(b + 1) * N + i]);
                v2 += __builtin_nontemporal_load(&partials[(size_t)(b + 2) * N + i]);
                v3 += __builtin_nontemporal_load(&partials[(size_t)(b + 3) * N + i]);
            }
            for (; b < B; ++b) v0 += partials[(size_t)b * N + i];
            v = (v0 + v1) + (v2 + v3);
            acc[i] = v;
        } else {
            v = acc[i];
        }
        float nm = fmaxf(m, v);
        l = l * __expf(m - nm) + __expf(v - nm);
        m = nm;
    }
    float mb = blockReduceMaxB(m);
    float ladj = (m == -INFINITY) ? 0.0f : l * __expf(m - mb);
    float lb = blockReduceSumB(ladj);
    if (threadIdx.x == 0) {
        red[blockIdx.x] = mb;
        red[STAT_BLOCKS + blockIdx.x] = lb;
    }
}

// ---------------- K4: finalize (redundant stat reduce + normalize) ---------
__global__ __launch_bounds__(256) void finalize_kernel(
    const float* __restrict__ acc,
    const float* __restrict__ red,
    float* __restrict__ out,
    int N)
{
    float m = red[threadIdx.x];
    float l = red[STAT_BLOCKS + threadIdx.x];
    float M = blockReduceMaxB(m);
    float L = blockReduceSumB(l * __expf(m - M));
    const float inv = 1.0f / L;

    int i = blockIdx.x * blockDim.x + threadIdx.x;
    if (i < N) out[i] = __expf(acc[i] - M) * inv;
}

// ---------------------------------------------------------------------------
extern "C" void kernel_launch(void* const* d_in, const int* in_sizes, int n_in,
                              void* d_out, int out_size, void* d_ws, size_t ws_size,
                              hipStream_t stream) {
    const float* h      = (const float*)d_in[0];
    const int*   ei     = (const int*)  d_in[1];
    const float* W_edge = (const float*)d_in[2];
    const float* b_edge = (const float*)d_in[3];
    const float* W_node = (const float*)d_in[4];
    const float* b_node = (const float*)d_in[5];

    const int H = in_sizes[2] / 2;            // W_edge has 2H elements
    const int N = in_sizes[0] / H;
    const int E = in_sizes[1] / 2;

    float* out      = (float*)d_out;
    float* ws       = (float*)d_ws;
    float* s_src    = ws;
    float* t_dst    = ws + (size_t)N;
    float* self_s   = ws + 2 * (size_t)N;
    float* acc      = ws + 3 * (size_t)N;
    float* red      = ws + 4 * (size_t)N;
    float* partials = red + 2 * STAT_BLOCKS;

    // Partial copies that fit
    const size_t base_floats = 4 * (size_t)N + 2 * STAT_BLOCKS;
    int B = 0;
    if (ws_size / sizeof(float) > base_floats) {
        size_t avail = ws_size / sizeof(float) - base_floats;
        B = (int)(avail / (size_t)N);
    }
    if (B > NCHUNKS) B = NCHUNKS;
    const int R = (N + RANGE_SIZE - 1) >> RANGE_BITS;
    const int use_partials = (B >= 16) ? 1 : 0;

    // 1) node scores
    {
        int threads = N * 16;
        int grid = (threads + 255) / 256;
        node_scores_kernel<<<grid, 256, 0, stream>>>(
            h, W_edge, b_edge, W_node, b_node,
            s_src, t_dst, self_s, acc, N, H);
    }
    // 2) edge accumulation
    if (use_partials) {
        int chunk = (((E + B - 1) / B) + 3) & ~3;   // 4-aligned chunk starts
        int vec_ok = ((E & 3) == 0) ? 1 : 0;
        dim3 grid(B, R);
        edge_bin_kernel<<<grid, 1024, 0, stream>>>(
            ei, s_src, t_dst, partials, N, E, chunk, vec_ok);
    } else {
        int grid = (E + 255) / 256;
        edge_accum_fallback_kernel<<<grid, 256, 0, stream>>>(ei, s_src, t_dst, acc, E);
    }
    // 3) combine + online softmax stats (fixed 256-block grid)
    combine_stats_kernel<<<STAT_BLOCKS, 256, 0, stream>>>(
        self_s, partials, acc, red, N, B, use_partials);
    // 4) finalize: redundant stat reduce per block + normalize
    {
        int grid = (N + 255) / 256;
        finalize_kernel<<<grid, 256, 0, stream>>>(acc, red, out, N);
    }
}

// Round 9
// 112.721 us; speedup vs baseline: 1.0960x; 1.0960x over previous
//
#include <hip/hip_runtime.h>
#include <math.h>

// ---------------------------------------------------------------------------
// RootCauseAttention: per-node scores -> edge segment-sum -> global softmax
//
// Structure (round 9 = round 6 revert + XCD swizzle + ILP2):
//  K1 node_scores: s_src, t_dst(=s_dst+b_edge), self(=s_node+b_node); 16
//     lanes/node, float4 loads.
//  K2 edge_bin: LDS histograms, NO global atomics (rounds 1-2: global fp32
//     atomics run ~18 G/s memory-side RMW regardless of scope). B=64 chunks
//     x R=4 ranges of 16384 (64 KB LDS), 1024 thr/block, grid 256.
//     Round 8 falsified the occupancy theory (B=128 / 32 waves/CU was
//     NEUTRAL on the scan and +4us on partials traffic) -> traffic-bound.
//     New: 1-D grid with XCD swizzle (id%8 = XCD round-robin assumed) so the
//     4 range-passes of one chunk share one XCD's L2; 2x-unrolled scan for
//     more overlapped L2 gather chains; src quad loaded unconditionally
//     (25% predicate density touches every line anyway).
//  K3 combine_stats: acc = self + sum_b partials; ONLINE softmax stats
//     (m,l) per block -> red[256|256]. No atomics, no grid.sync (round 4:
//     grid.sync spins ~59 us on this 8-XCD chip).
//  K4 finalize: every block redundantly reduces the 256 (m,l) pairs (2 KB,
//     L2-hot) -> (M,L), writes out = exp(acc-M)/L.
//
// Workspace (floats): s_src[N] | t_dst[N] | self[N] | acc[N] | red[512] |
//                     partials[B*N]
// ---------------------------------------------------------------------------

#define RANGE_BITS 14
#define RANGE_SIZE (1 << RANGE_BITS)   // 16384 nodes/range, 64 KB LDS
#define NCHUNKS 64
#define STAT_BLOCKS 256                // K3 grid size (fixed; red[] sizing)

typedef float vfloat4 __attribute__((ext_vector_type(4)));

// ---------------- K1: node scores (16 lanes/node, float4) ------------------
__global__ __launch_bounds__(256) void node_scores_kernel(
    const float* __restrict__ h,
    const float* __restrict__ W_edge,   // [2H]
    const float* __restrict__ b_edge,   // [1]
    const float* __restrict__ W_node,   // [H]
    const float* __restrict__ b_node,   // [1]
    float* __restrict__ s_src,
    float* __restrict__ t_dst,
    float* __restrict__ self_sc,
    float* __restrict__ acc,            // pre-init to self (fallback path)
    int N, int H)
{
    const int lane16 = threadIdx.x & 15;
    const int n = (blockIdx.x * blockDim.x + threadIdx.x) >> 4;
    if (n >= N) return;

    const float4* __restrict__ h4  = (const float4*)(h + (size_t)n * H);
    const float4* __restrict__ ws4 = (const float4*)(W_edge);
    const float4* __restrict__ wd4 = (const float4*)(W_edge + H);
    const float4* __restrict__ wn4 = (const float4*)(W_node);
    const int H4 = H >> 2;

    float ps = 0.0f, pd = 0.0f, pn = 0.0f;
    for (int i = lane16; i < H4; i += 16) {
        float4 hv = h4[i];
        float4 a = ws4[i], b = wd4[i], c = wn4[i];
        ps = fmaf(hv.x, a.x, fmaf(hv.y, a.y, fmaf(hv.z, a.z, fmaf(hv.w, a.w, ps))));
        pd = fmaf(hv.x, b.x, fmaf(hv.y, b.y, fmaf(hv.z, b.z, fmaf(hv.w, b.w, pd))));
        pn = fmaf(hv.x, c.x, fmaf(hv.y, c.y, fmaf(hv.z, c.z, fmaf(hv.w, c.w, pn))));
    }
    #pragma unroll
    for (int off = 8; off > 0; off >>= 1) {
        ps += __shfl_xor(ps, off, 64);
        pd += __shfl_xor(pd, off, 64);
        pn += __shfl_xor(pn, off, 64);
    }
    if (lane16 == 0) {
        float self = pn + b_node[0];
        s_src[n]   = ps;
        t_dst[n]   = pd + b_edge[0];
        self_sc[n] = self;
        acc[n]     = self;
    }
}

// ---------------- K2: LDS-histogram edge binning (XCD-swizzled) ------------
// Requires grid == 256 == NCHUNKS(64) * R(4). id%8 assumed = XCD; the four
// range-passes (r=0..3) of chunk b map to the same XCD for L2-local re-reads.
__global__ __launch_bounds__(1024) void edge_bin_swz_kernel(
    const int* __restrict__ ei,          // [2*E]: src row then dst row
    const float* __restrict__ s_src,
    const float* __restrict__ t_dst,
    float* __restrict__ partials,        // [64*N]
    int N, int E, int chunk, int vec_ok)
{
    __shared__ float hist[RANGE_SIZE];
    const int id = blockIdx.x;
    const int g  = id & 7;               // XCD slot
    const int s  = id >> 3;              // 0..31
    const int b  = (g << 3) | (s & 7);   // chunk 0..63 (8 chunks per XCD)
    const int r  = s >> 3;               // range 0..3
    const int lo = r << RANGE_BITS;
    const int hi = min(lo + RANGE_SIZE, N);
    const unsigned span = (unsigned)(hi - lo);

    {   // vector zeroing
        vfloat4* __restrict__ hz = (vfloat4*)hist;
        const vfloat4 z = {0.0f, 0.0f, 0.0f, 0.0f};
        for (int i = threadIdx.x; i < (RANGE_SIZE >> 2); i += blockDim.x)
            hz[i] = z;
    }
    __syncthreads();

    const int e0 = b * chunk;
    const int e1 = min(e0 + chunk, E);
    if (e0 < e1) {
        if (vec_ok) {
            const int nvec = (e1 - e0) >> 2;
            const int4* __restrict__ dst4 = (const int4*)(ei + E + e0);
            const int4* __restrict__ src4 = (const int4*)(ei + e0);
            int i = threadIdx.x;
            // 2x unrolled: two independent quads in flight per iteration
            for (; i + (int)blockDim.x < nvec; i += 2 * blockDim.x) {
                int4 da = dst4[i];
                int4 db = dst4[i + blockDim.x];
                int4 sa = src4[i];
                int4 sb = src4[i + blockDim.x];
                unsigned ax = (unsigned)(da.x - lo), ay = (unsigned)(da.y - lo);
                unsigned az = (unsigned)(da.z - lo), aw = (unsigned)(da.w - lo);
                if (ax < span) atomicAdd(&hist[ax], s_src[sa.x] + t_dst[da.x]);
                if (ay < span) atomicAdd(&hist[ay], s_src[sa.y] + t_dst[da.y]);
                if (az < span) atomicAdd(&hist[az], s_src[sa.z] + t_dst[da.z]);
                if (aw < span) atomicAdd(&hist[aw], s_src[sa.w] + t_dst[da.w]);
                unsigned bx = (unsigned)(db.x - lo), by = (unsigned)(db.y - lo);
                unsigned bz = (unsigned)(db.z - lo), bw = (unsigned)(db.w - lo);
                if (bx < span) atomicAdd(&hist[bx], s_src[sb.x] + t_dst[db.x]);
                if (by < span) atomicAdd(&hist[by], s_src[sb.y] + t_dst[db.y]);
                if (bz < span) atomicAdd(&hist[bz], s_src[sb.z] + t_dst[db.z]);
                if (bw < span) atomicAdd(&hist[bw], s_src[sb.w] + t_dst[db.w]);
            }
            if (i < nvec) {
                int4 da = dst4[i];
                int4 sa = src4[i];
                unsigned ax = (unsigned)(da.x - lo), ay = (unsigned)(da.y - lo);
                unsigned az = (unsigned)(da.z - lo), aw = (unsigned)(da.w - lo);
                if (ax < span) atomicAdd(&hist[ax], s_src[sa.x] + t_dst[da.x]);
                if (ay < span) atomicAdd(&hist[ay], s_src[sa.y] + t_dst[da.y]);
                if (az < span) atomicAdd(&hist[az], s_src[sa.z] + t_dst[da.z]);
                if (aw < span) atomicAdd(&hist[aw], s_src[sa.w] + t_dst[da.w]);
            }
            for (int e = e0 + 4 * nvec + threadIdx.x; e < e1; e += blockDim.x) {
                int d = ei[E + e];
                unsigned u = (unsigned)(d - lo);
                if (u < span) atomicAdd(&hist[u], s_src[ei[e]] + t_dst[d]);
            }
        } else {
            for (int e = e0 + threadIdx.x; e < e1; e += blockDim.x) {
                int d = ei[E + e];
                unsigned u = (unsigned)(d - lo);
                if (u < span) atomicAdd(&hist[u], s_src[ei[e]] + t_dst[d]);
            }
        }
    }
    __syncthreads();

    float* __restrict__ outp = partials + (size_t)b * N + lo;
    const int len = hi - lo;
    if ((len & 3) == 0) {
        const int len4 = len >> 2;
        const vfloat4* __restrict__ h4 = (const vfloat4*)hist;
        vfloat4* __restrict__ o4 = (vfloat4*)outp;
        for (int i = threadIdx.x; i < len4; i += blockDim.x) o4[i] = h4[i];
    } else {
        for (int i = threadIdx.x; i < len; i += blockDim.x) outp[i] = hist[i];
    }
}

// Generic 2-D fallback (any B, R) — same algorithm, no swizzle.
__global__ __launch_bounds__(1024) void edge_bin_kernel(
    const int* __restrict__ ei,
    const float* __restrict__ s_src,
    const float* __restrict__ t_dst,
    float* __restrict__ partials,
    int N, int E, int chunk, int vec_ok)
{
    __shared__ float hist[RANGE_SIZE];
    const int b  = blockIdx.x;
    const int r  = blockIdx.y;
    const int lo = r << RANGE_BITS;
    const int hi = min(lo + RANGE_SIZE, N);
    const unsigned span = (unsigned)(hi - lo);

    for (int i = threadIdx.x; i < RANGE_SIZE; i += blockDim.x) hist[i] = 0.0f;
    __syncthreads();

    const int e0 = b * chunk;
    const int e1 = min(e0 + chunk, E);
    if (e0 < e1) {
        if (vec_ok) {
            const int nvec = (e1 - e0) >> 2;
            const int4* __restrict__ dst4 = (const int4*)(ei + E + e0);
            const int4* __restrict__ src4 = (const int4*)(ei + e0);
            for (int i = threadIdx.x; i < nvec; i += blockDim.x) {
                int4 d = dst4[i];
                int4 s = src4[i];
                unsigned ux = (unsigned)(d.x - lo), uy = (unsigned)(d.y - lo);
                unsigned uz = (unsigned)(d.z - lo), uw = (unsigned)(d.w - lo);
                if (ux < span) atomicAdd(&hist[ux], s_src[s.x] + t_dst[d.x]);
                if (uy < span) atomicAdd(&hist[uy], s_src[s.y] + t_dst[d.y]);
                if (uz < span) atomicAdd(&hist[uz], s_src[s.z] + t_dst[d.z]);
                if (uw < span) atomicAdd(&hist[uw], s_src[s.w] + t_dst[d.w]);
            }
            for (int e = e0 + 4 * nvec + threadIdx.x; e < e1; e += blockDim.x) {
                int d = ei[E + e];
                unsigned u = (unsigned)(d - lo);
                if (u < span) atomicAdd(&hist[u], s_src[ei[e]] + t_dst[d]);
            }
        } else {
            for (int e = e0 + threadIdx.x; e < e1; e += blockDim.x) {
                int d = ei[E + e];
                unsigned u = (unsigned)(d - lo);
                if (u < span) atomicAdd(&hist[u], s_src[ei[e]] + t_dst[d]);
            }
        }
    }
    __syncthreads();

    float* __restrict__ outp = partials + (size_t)b * N + lo;
    const int len = hi - lo;
    for (int i = threadIdx.x; i < len; i += blockDim.x) outp[i] = hist[i];
}

// Fallback edge path (tiny workspace): agent-scope atomics into acc.
__global__ __launch_bounds__(256) void edge_accum_fallback_kernel(
    const int* __restrict__ ei,
    const float* __restrict__ s_src,
    const float* __restrict__ t_dst,
    float* __restrict__ acc,
    int E)
{
    int e = blockIdx.x * blockDim.x + threadIdx.x;
    if (e >= E) return;
    int s = ei[e];
    int d = ei[E + e];
    atomicAdd(&acc[d], s_src[s] + t_dst[d]);
}

// ---------------- block reduction helpers ----------------------------------
__device__ __forceinline__ float blockReduceMaxB(float v) {
    __shared__ float sm[16];
    #pragma unroll
    for (int off = 32; off > 0; off >>= 1) v = fmaxf(v, __shfl_xor(v, off, 64));
    const int w = threadIdx.x >> 6, l = threadIdx.x & 63;
    const int nw = blockDim.x >> 6;
    if (l == 0) sm[w] = v;
    __syncthreads();
    float r = sm[0];
    for (int i = 1; i < nw; ++i) r = fmaxf(r, sm[i]);
    __syncthreads();
    return r;
}

__device__ __forceinline__ float blockReduceSumB(float v) {
    __shared__ float sm[16];
    #pragma unroll
    for (int off = 32; off > 0; off >>= 1) v += __shfl_xor(v, off, 64);
    const int w = threadIdx.x >> 6, l = threadIdx.x & 63;
    const int nw = blockDim.x >> 6;
    if (l == 0) sm[w] = v;
    __syncthreads();
    float r = 0.0f;
    for (int i = 0; i < nw; ++i) r += sm[i];
    __syncthreads();
    return r;
}

// ---------------- K3: combine + online softmax stats -----------------------
// Grid MUST be STAT_BLOCKS blocks. red[b] = m_b, red[STAT_BLOCKS+b] = l_b.
__global__ __launch_bounds__(256) void combine_stats_kernel(
    const float* __restrict__ self_sc,
    const float* __restrict__ partials,
    float* __restrict__ acc,
    float* __restrict__ red,
    int N, int B, int use_partials)
{
    float m = -INFINITY, l = 0.0f;
    for (int i = blockIdx.x * blockDim.x + threadIdx.x; i < N;
         i += gridDim.x * blockDim.x) {
        float v;
        if (use_partials) {
            float v0 = self_sc[i], v1 = 0.0f, v2 = 0.0f, v3 = 0.0f;
            int b = 0;
            for (; b + 4 <= B; b += 4) {
                v0 += partials[(size_t)(b + 0) * N + i];
                v1 += partials[(size_t)(b + 1) * N + i];
                v2 += partials[(size_t)(b + 2) * N + i];
                v3 += partials[(size_t)(b + 3) * N + i];
            }
            for (; b < B; ++b) v0 += partials[(size_t)b * N + i];
            v = (v0 + v1) + (v2 + v3);
            acc[i] = v;
        } else {
            v = acc[i];
        }
        float nm = fmaxf(m, v);
        l = l * __expf(m - nm) + __expf(v - nm);
        m = nm;
    }
    float mb = blockReduceMaxB(m);
    float ladj = (m == -INFINITY) ? 0.0f : l * __expf(m - mb);
    float lb = blockReduceSumB(ladj);
    if (threadIdx.x == 0) {
        red[blockIdx.x] = mb;
        red[STAT_BLOCKS + blockIdx.x] = lb;
    }
}

// ---------------- K4: finalize (redundant stat reduce + normalize) ---------
__global__ __launch_bounds__(256) void finalize_kernel(
    const float* __restrict__ acc,
    const float* __restrict__ red,
    float* __restrict__ out,
    int N)
{
    float m = red[threadIdx.x];
    float l = red[STAT_BLOCKS + threadIdx.x];
    float M = blockReduceMaxB(m);
    float L = blockReduceSumB(l * __expf(m - M));
    const float inv = 1.0f / L;

    int i = blockIdx.x * blockDim.x + threadIdx.x;
    if (i < N) out[i] = __expf(acc[i] - M) * inv;
}

// ---------------------------------------------------------------------------
extern "C" void kernel_launch(void* const* d_in, const int* in_sizes, int n_in,
                              void* d_out, int out_size, void* d_ws, size_t ws_size,
                              hipStream_t stream) {
    const float* h      = (const float*)d_in[0];
    const int*   ei     = (const int*)  d_in[1];
    const float* W_edge = (const float*)d_in[2];
    const float* b_edge = (const float*)d_in[3];
    const float* W_node = (const float*)d_in[4];
    const float* b_node = (const float*)d_in[5];

    const int H = in_sizes[2] / 2;            // W_edge has 2H elements
    const int N = in_sizes[0] / H;
    const int E = in_sizes[1] / 2;

    float* out      = (float*)d_out;
    float* ws       = (float*)d_ws;
    float* s_src    = ws;
    float* t_dst    = ws + (size_t)N;
    float* self_s   = ws + 2 * (size_t)N;
    float* acc      = ws + 3 * (size_t)N;
    float* red      = ws + 4 * (size_t)N;
    float* partials = red + 2 * STAT_BLOCKS;

    // Partial copies that fit
    const size_t base_floats = 4 * (size_t)N + 2 * STAT_BLOCKS;
    int B = 0;
    if (ws_size / sizeof(float) > base_floats) {
        size_t avail = ws_size / sizeof(float) - base_floats;
        B = (int)(avail / (size_t)N);
    }
    if (B > NCHUNKS) B = NCHUNKS;
    const int R = (N + RANGE_SIZE - 1) >> RANGE_BITS;
    const int use_partials = (B >= 16) ? 1 : 0;

    // 1) node scores
    {
        int threads = N * 16;
        int grid = (threads + 255) / 256;
        node_scores_kernel<<<grid, 256, 0, stream>>>(
            h, W_edge, b_edge, W_node, b_node,
            s_src, t_dst, self_s, acc, N, H);
    }
    // 2) edge accumulation
    if (use_partials) {
        int chunk = (((E + B - 1) / B) + 3) & ~3;   // 4-aligned chunk starts
        int vec_ok = ((E & 3) == 0) ? 1 : 0;
        if (B == NCHUNKS && R == 4) {
            // XCD-swizzled 1-D grid: 4 range-passes of a chunk share an XCD
            edge_bin_swz_kernel<<<256, 1024, 0, stream>>>(
                ei, s_src, t_dst, partials, N, E, chunk, vec_ok);
        } else {
            dim3 grid(B, R);
            edge_bin_kernel<<<grid, 1024, 0, stream>>>(
                ei, s_src, t_dst, partials, N, E, chunk, vec_ok);
        }
    } else {
        int grid = (E + 255) / 256;
        edge_accum_fallback_kernel<<<grid, 256, 0, stream>>>(ei, s_src, t_dst, acc, E);
    }
    // 3) combine + online softmax stats (fixed 256-block grid)
    combine_stats_kernel<<<STAT_BLOCKS, 256, 0, stream>>>(
        self_s, partials, acc, red, N, B, use_partials);
    // 4) finalize: redundant stat reduce per block + normalize
    {
        int grid = (N + 255) / 256;
        finalize_kernel<<<grid, 256, 0, stream>>>(acc, red, out, N);
    }
}